// Round 11
// baseline (22863.644 us; speedup 1.0000x reference)
//
#include <hip/hip_runtime.h>
#include <math.h>

// NCA: B=8, H=W=256, C=16, 16 steps. fp32.
// R10 post-mortem: LDS 54272*3 = 162.8KB > usable pool -> only 2 blocks/CU
// (occ 23%); perc reads ~3-way conflicted (8.8e7 counter).
// R11: additive bank-rotation layouts:
//   perc [64][128] tight, chan (g,w) at p*128+g*32+((w+4*((p&7)+2g &7))&31)
//     -> read lanes (quad,kq) hit group quad+2kq mod 8: exactly 2-way = free.
//   w0s [128][32], col rotated by 4*(row&7): read banks 8jg+4kq+16k' = 2-way.
// LDS 50.3KB -> 3 blocks/CU guaranteed. Phase-1 8-way writes/conv accepted.

#define HW 256
#define NPIX (8*HW*HW)   // 524288

__device__ __forceinline__ float4 f4max(float4 a, float4 b) {
    return make_float4(fmaxf(a.x,b.x), fmaxf(a.y,b.y), fmaxf(a.z,b.z), fmaxf(a.w,b.w));
}

// Precompute sobel bank (6 filters, 7x7, normalized).
__global__ void init_kernel(const float* __restrict__ W0,
                            float* __restrict__ filt) {
    int t = blockIdx.x * blockDim.x + threadIdx.x;
    if (t < 6) {
        int f = t;
        int size = 3 + 2*(f >> 1);
        int p0 = (7 - size) >> 1;
        int isY = f & 1;
        float vals[49];
        float norm = 0.f;
        for (int a = 0; a < 7; a++) {
            for (int b = 0; b < 7; b++) {
                float v = 0.f;
                if (a >= p0 && a < p0+size && b >= p0 && b < p0+size) {
                    float fy = (float)(a - 3), fx = (float)(b - 3);
                    float den = fx*fx + fy*fy;
                    if (den == 0.f) den = 1.f;
                    v = (isY ? fy : fx) / den;
                }
                vals[a*7+b] = v;
                norm += fabsf(v);
            }
        }
        float inv = 1.f / norm;
        for (int i = 0; i < 49; i++) filt[f*49 + i] = vals[i] * inv;
    }
}

// One 8x8 pixel tile per block, 256 threads.
__launch_bounds__(256, 3)
__global__ void step_main(const float* __restrict__ x,
                          float* __restrict__ xmid,
                          float* __restrict__ alpha_out,
                          float* __restrict__ prelife_out,
                          const float* __restrict__ filt_g,
                          const float* __restrict__ W0,
                          const float* __restrict__ b0,
                          const float* __restrict__ W1,
                          const float* __restrict__ stoch_s) {
    // carve: [0,4096) w0s (phase2) / xs 3920 (phase1)
    //        [4096,12288) perc 64x128 rotated
    //        [12288,12582) filt
    // total 12582 fl = 50328 B -> 3 blocks/CU (151 KB)
    __shared__ float smem[12582];
    float* xs     = smem;            // 14*14*20 = 3920 (phase 1 only)
    float* w0s    = smem;            // 128 rows x 32 rotated (phase 2 only)
    float* perc   = smem + 4096;     // 64 x 128 rotated
    float* filt_s = smem + 12288;    // 294

    const int t   = threadIdx.x;
    const int b   = blockIdx.z;
    const int ty0 = blockIdx.y * 8;
    const int tx0 = blockIdx.x * 8;

    for (int i = t; i < 294; i += 256) filt_s[i] = filt_g[i];

    // stage x tile + halo (zero pad = conv's zero padding)
    for (int v = t; v < 784; v += 256) {          // 14*14*4 float4s
        int c4  = v & 3;
        int cell = v >> 2;
        int ly = cell / 14;
        int lx = cell - ly*14;
        int gy = ty0 + ly - 3, gx = tx0 + lx - 3;
        float4 val = make_float4(0.f,0.f,0.f,0.f);
        if ((unsigned)gy < 256u && (unsigned)gx < 256u)
            val = *(const float4*)&x[((((b<<8) + gy)<<8) + gx)*16 + (c4<<2)];
        *(float4*)&xs[cell*20 + (c4<<2)] = val;
    }
    __syncthreads();

    {   // ---- phase 1: conv + pools -> perc (rotated layout) ----
        const int p  = t & 63;
        const int q  = t >> 6;
        const int py = p >> 3, px = p & 7;
        const int gy = ty0 + py, gx = tx0 + px;
        const int q4 = q << 2;

        float4 y4[6];
        #pragma unroll
        for (int f = 0; f < 6; f++) y4[f] = make_float4(0.f,0.f,0.f,0.f);

        #pragma unroll
        for (int a = 0; a < 7; a++) {
            #pragma unroll
            for (int bb = 0; bb < 7; bb++) {
                float4 xv = *(const float4*)&xs[((py+a)*14 + (px+bb))*20 + q4];
                #pragma unroll
                for (int f = 0; f < 6; f++) {
                    float w = filt_s[f*49 + a*7 + bb];
                    y4[f].x = fmaf(w, xv.x, y4[f].x);
                    y4[f].y = fmaf(w, xv.y, y4[f].y);
                    y4[f].z = fmaf(w, xv.z, y4[f].z);
                    y4[f].w = fmaf(w, xv.w, y4[f].w);
                }
            }
        }
        float4 m5 = make_float4(-INFINITY,-INFINITY,-INFINITY,-INFINITY);
        #pragma unroll
        for (int dy = -2; dy <= 2; dy++) {
            #pragma unroll
            for (int dx2 = -2; dx2 <= 2; dx2++) {
                if ((unsigned)(gy+dy) < 256u && (unsigned)(gx+dx2) < 256u)
                    m5 = f4max(m5, *(const float4*)&xs[((py+3+dy)*14 + (px+3+dx2))*20 + q4]);
            }
        }
        // rotated stores: group g rotation R_g = 4*(((p&7)+2g)&7)
        const int p7 = p & 7;
        const int R0 = ((p7    ) & 7) << 2;
        const int R1 = ((p7 + 2) & 7) << 2;
        const int R2 = ((p7 + 4) & 7) << 2;
        const int R3 = ((p7 + 6) & 7) << 2;
        float* pr = &perc[p << 7];
        float4 xc = *(const float4*)&xs[((py+3)*14 + (px+3))*20 + q4];
        *(float4*)&pr[      ((q4      + R0) & 31)] = xc;       // x: c=q4
        *(float4*)&pr[      ((16 + q4 + R0) & 31)] = y4[0];    // c=16+q4
        *(float4*)&pr[32  + ((q4      + R1) & 31)] = y4[1];    // c=32+q4
        *(float4*)&pr[32  + ((16 + q4 + R1) & 31)] = y4[2];    // c=48+q4
        *(float4*)&pr[64  + ((q4      + R2) & 31)] = y4[3];    // c=64+q4
        *(float4*)&pr[64  + ((16 + q4 + R2) & 31)] = y4[4];    // c=80+q4
        *(float4*)&pr[96  + ((q4      + R3) & 31)] = y4[5];    // c=96+q4
        *(float4*)&pr[96  + ((16 + q4 + R3) & 31)] = m5;       // pool5

        if (q == 0) {
            float pre = -INFINITY;
            #pragma unroll
            for (int dy = -1; dy <= 1; dy++) {
                #pragma unroll
                for (int dx2 = -1; dx2 <= 1; dx2++) {
                    if ((unsigned)(gy+dy) < 256u && (unsigned)(gx+dx2) < 256u)
                        pre = fmaxf(pre, xs[((py+3+dy)*14 + (px+3+dx2))*20 + 3]);
                }
            }
            prelife_out[(b << 16) + (gy << 8) + gx] = (pre > 0.1f) ? 1.f : 0.f;
        }
    }

    // ---- phase 2: MLP ----
    const int kq   = t & 3;         // k-quarter + output channel-quad
    const int jg   = (t >> 2) & 3;  // j-octet within 32-j chunk
    const int quad = t >> 4;        // pixel quad: owns px {quad+16i}
    const int jg8  = jg << 3;
    const int Rp   = ((quad + (kq << 1)) & 7) << 2;   // perc read rotation

    const float* pp0 = &perc[((quad     ) << 7) + (kq << 5)];
    const float* pp1 = &perc[((quad + 16) << 7) + (kq << 5)];
    const float* pp2 = &perc[((quad + 32) << 7) + (kq << 5)];
    const float* pp3 = &perc[((quad + 48) << 7) + (kq << 5)];

    // staging: thread handles float4 idx r*256+t; kg = r*32+u, u=t>>3, jp=t&7
    const int u  = t >> 3;
    const int jp = t & 7;
    const float* pW = W0 + (u << 8) + (jp << 2);      // + r*8192 + jc*32
    // dest row = u*4 + r; col = (jp*4 + 4*(row&7)) & 31
    const int row0 = (u << 2) + 0, col0 = (((jp << 2) + ((row0 & 7) << 2)) & 31);
    const int row1 = (u << 2) + 1, col1 = (((jp << 2) + ((row1 & 7) << 2)) & 31);
    const int row2 = (u << 2) + 2, col2 = (((jp << 2) + ((row2 & 7) << 2)) & 31);
    const int row3 = (u << 2) + 3, col3 = (((jp << 2) + ((row3 & 7) << 2)) & 31);
    const int wd0 = (row0 << 5) + col0;
    const int wd1 = (row1 << 5) + col1;
    const int wd2 = (row2 << 5) + col2;
    const int wd3 = (row3 << 5) + col3;

    float dx[4][4];
    #pragma unroll
    for (int i = 0; i < 4; i++)
        #pragma unroll
        for (int c = 0; c < 4; c++) dx[i][c] = 0.f;

    // prologue: stage chunk 0
    float4 st0 = *(const float4*)(pW);
    float4 st1 = *(const float4*)(pW +  8192);
    float4 st2 = *(const float4*)(pW + 16384);
    float4 st3 = *(const float4*)(pW + 24576);
    __syncthreads();   // phase-1 xs reads + perc writes complete
    *(float4*)&w0s[wd0] = st0;
    *(float4*)&w0s[wd1] = st1;
    *(float4*)&w0s[wd2] = st2;
    *(float4*)&w0s[wd3] = st3;
    __syncthreads();

    #pragma unroll 1
    for (int jc = 0; jc < 8; jc++) {
        // T14: issue next chunk's loads now; latency hides under the FMAs
        if (jc < 7) {
            const float* pN = pW + ((jc + 1) << 5);
            st0 = *(const float4*)(pN);
            st1 = *(const float4*)(pN +  8192);
            st2 = *(const float4*)(pN + 16384);
            st3 = *(const float4*)(pN + 24576);
        }

        float h[4][8];
        #pragma unroll
        for (int i = 0; i < 4; i++)
            #pragma unroll
            for (int jj = 0; jj < 8; jj++) h[i][jj] = 0.f;

        #pragma unroll 2
        for (int k4 = 0; k4 < 32; k4 += 4) {
            const int o = (k4 + Rp) & 31;        // rotated perc offset
            float4 pA0 = *(const float4*)&pp0[o];
            float4 pA1 = *(const float4*)&pp1[o];
            float4 pA2 = *(const float4*)&pp2[o];
            float4 pA3 = *(const float4*)&pp3[o];
            #pragma unroll
            for (int kk = 0; kk < 4; kk++) {
                float a0 = kk==0?pA0.x : kk==1?pA0.y : kk==2?pA0.z : pA0.w;
                float a1 = kk==0?pA1.x : kk==1?pA1.y : kk==2?pA1.z : pA1.w;
                float a2 = kk==0?pA2.x : kk==1?pA2.y : kk==2?pA2.z : pA2.w;
                float a3 = kk==0?pA3.x : kk==1?pA3.y : kk==2?pA3.z : pA3.w;
                const int row = ((k4 + kk) << 2) + kq;
                const int rot = (row & 7) << 2;
                const float* wr = &w0s[row << 5];
                float4 wA = *(const float4*)&wr[(jg8     + rot) & 31];
                float4 wB = *(const float4*)&wr[(jg8 + 4 + rot) & 31];
                #pragma unroll
                for (int i = 0; i < 4; i++) {
                    float ai = i==0?a0 : i==1?a1 : i==2?a2 : a3;
                    h[i][0] = fmaf(ai, wA.x, h[i][0]);
                    h[i][1] = fmaf(ai, wA.y, h[i][1]);
                    h[i][2] = fmaf(ai, wA.z, h[i][2]);
                    h[i][3] = fmaf(ai, wA.w, h[i][3]);
                    h[i][4] = fmaf(ai, wB.x, h[i][4]);
                    h[i][5] = fmaf(ai, wB.y, h[i][5]);
                    h[i][6] = fmaf(ai, wB.z, h[i][6]);
                    h[i][7] = fmaf(ai, wB.w, h[i][7]);
                }
            }
        }
        // reduce h over the 4 kq lanes (bits 0-1)
        #pragma unroll
        for (int i = 0; i < 4; i++)
            #pragma unroll
            for (int jj = 0; jj < 8; jj++) {
                h[i][jj] += __shfl_xor(h[i][jj], 1);
                h[i][jj] += __shfl_xor(h[i][jj], 2);
            }
        // bias + relu
        const int jbase = (jc << 5) + jg8;
        float4 bA = *(const float4*)&b0[jbase];
        float4 bB = *(const float4*)&b0[jbase + 4];
        #pragma unroll
        for (int i = 0; i < 4; i++) {
            h[i][0] = fmaxf(h[i][0] + bA.x, 0.f);
            h[i][1] = fmaxf(h[i][1] + bA.y, 0.f);
            h[i][2] = fmaxf(h[i][2] + bA.z, 0.f);
            h[i][3] = fmaxf(h[i][3] + bA.w, 0.f);
            h[i][4] = fmaxf(h[i][4] + bB.x, 0.f);
            h[i][5] = fmaxf(h[i][5] + bB.y, 0.f);
            h[i][6] = fmaxf(h[i][6] + bB.z, 0.f);
            h[i][7] = fmaxf(h[i][7] + bB.w, 0.f);
        }
        // GEMM2: this lane's channel-quad kq*4..+4
        #pragma unroll
        for (int jj = 0; jj < 8; jj++) {
            float4 wv = *(const float4*)&W1[((jbase + jj) << 4) + (kq << 2)];
            #pragma unroll
            for (int i = 0; i < 4; i++) {
                dx[i][0] = fmaf(h[i][jj], wv.x, dx[i][0]);
                dx[i][1] = fmaf(h[i][jj], wv.y, dx[i][1]);
                dx[i][2] = fmaf(h[i][jj], wv.z, dx[i][2]);
                dx[i][3] = fmaf(h[i][jj], wv.w, dx[i][3]);
            }
        }

        __syncthreads();   // all reads of w0s done before overwrite
        if (jc < 7) {
            *(float4*)&w0s[wd0] = st0;
            *(float4*)&w0s[wd1] = st1;
            *(float4*)&w0s[wd2] = st2;
            *(float4*)&w0s[wd3] = st3;
            __syncthreads();
        }
    }

    // reduce dx over the 4 jg lanes (bits 2-3)
    #pragma unroll
    for (int i = 0; i < 4; i++)
        #pragma unroll
        for (int c = 0; c < 4; c++) {
            dx[i][c] += __shfl_xor(dx[i][c], 4);
            dx[i][c] += __shfl_xor(dx[i][c], 8);
        }

    // writer: pixel quad+16*jg, channels kq*4..+4
    float o0 = jg==0?dx[0][0] : jg==1?dx[1][0] : jg==2?dx[2][0] : dx[3][0];
    float o1 = jg==0?dx[0][1] : jg==1?dx[1][1] : jg==2?dx[2][1] : dx[3][1];
    float o2 = jg==0?dx[0][2] : jg==1?dx[1][2] : jg==2?dx[2][2] : dx[3][2];
    float o3 = jg==0?dx[0][3] : jg==1?dx[1][3] : jg==2?dx[2][3] : dx[3][3];

    const int pw  = quad + (jg << 4);
    const int ppy = pw >> 3, ppx = pw & 7;
    const int pix2 = (b << 16) + ((ty0 + ppy) << 8) + (tx0 + ppx);
    float fire = (stoch_s[pix2] > 0.5f) ? 1.f : 0.f;
    // xc2: channels kq*4..+3 are in group 0, rotation R0 = 4*(pw&7)
    float4 xc2 = *(const float4*)&perc[(pw << 7) + (((kq << 2) + ((pw & 7) << 2)) & 31)];
    float4 xn;
    xn.x = fmaf(fire, o0, xc2.x);
    xn.y = fmaf(fire, o1, xc2.y);
    xn.z = fmaf(fire, o2, xc2.z);
    xn.w = fmaf(fire, o3, xc2.w);
    *(float4*)&xmid[((size_t)pix2 << 4) + (kq << 2)] = xn;
    if (kq == 0) alpha_out[pix2] = xn.w;   // channel 3
}

// In-place life masking: reads alpha_new from the separate plane (race-free).
__global__ void step_mask(float* __restrict__ xbuf,
                          const float* __restrict__ alpha,
                          const float* __restrict__ prelife,
                          const float* __restrict__ valid) {
    int pix = blockIdx.x * 256 + threadIdx.x;
    int b = pix >> 16;
    int y = (pix >> 8) & 255;
    int x = pix & 255;
    float m = -INFINITY;
    #pragma unroll
    for (int dy = -1; dy <= 1; dy++) {
        #pragma unroll
        for (int dxo = -1; dxo <= 1; dxo++) {
            int yy = y + dy, xx = x + dxo;
            if ((unsigned)yy < 256u && (unsigned)xx < 256u)
                m = fmaxf(m, alpha[(b << 16) + (yy << 8) + xx]);
        }
    }
    float life = (prelife[pix] != 0.f && m > 0.1f) ? 1.f : 0.f;
    float s = life * valid[pix];
    float4* xp = (float4*)&xbuf[(size_t)pix << 4];
    #pragma unroll
    for (int i = 0; i < 4; i++) {
        float4 v = xp[i];
        v.x *= s; v.y *= s; v.z *= s; v.w *= s;
        xp[i] = v;
    }
}

extern "C" void kernel_launch(void* const* d_in, const int* in_sizes, int n_in,
                              void* d_out, int out_size, void* d_ws, size_t ws_size,
                              hipStream_t stream) {
    const float* x0    = (const float*)d_in[0];
    const float* valid = (const float*)d_in[1];
    const float* stoch = (const float*)d_in[2];
    const float* W0    = (const float*)d_in[3];
    const float* b0    = (const float*)d_in[4];
    const float* W1    = (const float*)d_in[5];

    float* ws      = (float*)d_ws;
    float* xA      = ws;                 // 8388608 floats
    float* alpha   = ws + 8388608;       // 524288
    float* prelife = ws + 8912896;       // 524288
    float* filt    = ws + 9437184;       // 294 (+pad)
    float* out     = (float*)d_out;

    init_kernel<<<1, 64, 0, stream>>>(W0, filt);

    const float* src = x0;
    for (int k = 1; k <= 16; k++) {
        float* dst = (k & 1) ? xA : out;   // step 16 (even) lands in d_out
        step_main<<<dim3(32,32,8), 256, 0, stream>>>(
            src, dst, alpha, prelife, filt, W0, b0, W1,
            stoch + (size_t)(k-1)*NPIX);
        step_mask<<<NPIX/256, 256, 0, stream>>>(dst, alpha, prelife, valid);
        src = dst;
    }
}

// Round 12
// 21000.150 us; speedup vs baseline: 1.0887x; 1.0887x over previous
//
#include <hip/hip_runtime.h>
#include <math.h>

// NCA: B=8, H=W=256, C=16, 16 steps. fp32.
// R11 post-mortem: rotation layouts left SQ_LDS_BANK_CONFLICT bit-identical
// (8.835e7) -> counter tracks LDS instr count, not layout; rotation's extra
// VALU regressed wall time. Reverted to R10 structure.
// R12: (1) consecutive-px mapping {4quad+i}: perc-read bank starts
// 16(quad&1)+4kq = uniform, conflict-free, zero extra VALU;
// (2) full k4 unroll for scheduling depth.

#define HW 256
#define NPIX (8*HW*HW)   // 524288
#define PST 140          // perc row stride (floats)
#define GST 36           // perc k-group stride (floats)

__device__ __forceinline__ float4 f4max(float4 a, float4 b) {
    return make_float4(fmaxf(a.x,b.x), fmaxf(a.y,b.y), fmaxf(a.z,b.z), fmaxf(a.w,b.w));
}

// Precompute sobel bank (6 filters, 7x7, normalized).
__global__ void init_kernel(const float* __restrict__ W0,
                            float* __restrict__ filt) {
    int t = blockIdx.x * blockDim.x + threadIdx.x;
    if (t < 6) {
        int f = t;
        int size = 3 + 2*(f >> 1);
        int p0 = (7 - size) >> 1;
        int isY = f & 1;
        float vals[49];
        float norm = 0.f;
        for (int a = 0; a < 7; a++) {
            for (int b = 0; b < 7; b++) {
                float v = 0.f;
                if (a >= p0 && a < p0+size && b >= p0 && b < p0+size) {
                    float fy = (float)(a - 3), fx = (float)(b - 3);
                    float den = fx*fx + fy*fy;
                    if (den == 0.f) den = 1.f;
                    v = (isY ? fy : fx) / den;
                }
                vals[a*7+b] = v;
                norm += fabsf(v);
            }
        }
        float inv = 1.f / norm;
        for (int i = 0; i < 49; i++) filt[f*49 + i] = vals[i] * inv;
    }
}

// One 8x8 pixel tile per block, 256 threads.
__launch_bounds__(256, 3)
__global__ void step_main(const float* __restrict__ x,
                          float* __restrict__ xmid,
                          float* __restrict__ alpha_out,
                          float* __restrict__ prelife_out,
                          const float* __restrict__ filt_g,
                          const float* __restrict__ W0,
                          const float* __restrict__ b0,
                          const float* __restrict__ W1,
                          const float* __restrict__ stoch_s) {
    // carve: phase1 [0,4214): xs 3920 + filt 294 | phase2 [0,4608): w0s
    //        perc [4608,13568)  -> 54272 B total
    __shared__ float smem[13568];
    float* xs     = smem;          // 14*14*20 = 3920 (phase 1 only)
    float* filt_s = smem + 3920;   // 294 (phase 1 only)
    float* w0s    = smem;          // 128 rows x 36 (phase 2 only)
    float* perc   = smem + 4608;   // 64 x 140

    const int t   = threadIdx.x;
    const int b   = blockIdx.z;
    const int ty0 = blockIdx.y * 8;
    const int tx0 = blockIdx.x * 8;

    for (int i = t; i < 294; i += 256) filt_s[i] = filt_g[i];

    // stage x tile + halo (zero pad = conv's zero padding)
    for (int v = t; v < 784; v += 256) {          // 14*14*4 float4s
        int c4  = v & 3;
        int cell = v >> 2;
        int ly = cell / 14;
        int lx = cell - ly*14;
        int gy = ty0 + ly - 3, gx = tx0 + lx - 3;
        float4 val = make_float4(0.f,0.f,0.f,0.f);
        if ((unsigned)gy < 256u && (unsigned)gx < 256u)
            val = *(const float4*)&x[((((b<<8) + gy)<<8) + gx)*16 + (c4<<2)];
        *(float4*)&xs[cell*20 + (c4<<2)] = val;
    }
    __syncthreads();

    {   // ---- phase 1: conv + pools -> perc ----
        const int p  = t & 63;
        const int q  = t >> 6;
        const int py = p >> 3, px = p & 7;
        const int gy = ty0 + py, gx = tx0 + px;
        const int q4 = q << 2;

        float4 y4[6];
        #pragma unroll
        for (int f = 0; f < 6; f++) y4[f] = make_float4(0.f,0.f,0.f,0.f);

        #pragma unroll
        for (int a = 0; a < 7; a++) {
            #pragma unroll
            for (int bb = 0; bb < 7; bb++) {
                float4 xv = *(const float4*)&xs[((py+a)*14 + (px+bb))*20 + q4];
                #pragma unroll
                for (int f = 0; f < 6; f++) {
                    float w = filt_s[f*49 + a*7 + bb];
                    y4[f].x = fmaf(w, xv.x, y4[f].x);
                    y4[f].y = fmaf(w, xv.y, y4[f].y);
                    y4[f].z = fmaf(w, xv.z, y4[f].z);
                    y4[f].w = fmaf(w, xv.w, y4[f].w);
                }
            }
        }
        float4 m5 = make_float4(-INFINITY,-INFINITY,-INFINITY,-INFINITY);
        #pragma unroll
        for (int dy = -2; dy <= 2; dy++) {
            #pragma unroll
            for (int dx2 = -2; dx2 <= 2; dx2++) {
                if ((unsigned)(gy+dy) < 256u && (unsigned)(gx+dx2) < 256u)
                    m5 = f4max(m5, *(const float4*)&xs[((py+3+dy)*14 + (px+3+dx2))*20 + q4]);
            }
        }
        // perc channel c stored at (c>>5)*GST + (c&31)
        float4 xc = *(const float4*)&xs[((py+3)*14 + (px+3))*20 + q4];
        *(float4*)&perc[p*PST + q4] = xc;
        const int offY[6] = {16, 36, 52, 72, 88, 108};
        #pragma unroll
        for (int f = 0; f < 6; f++)
            *(float4*)&perc[p*PST + offY[f] + q4] = y4[f];
        *(float4*)&perc[p*PST + 124 + q4] = m5;

        if (q == 0) {
            float pre = -INFINITY;
            #pragma unroll
            for (int dy = -1; dy <= 1; dy++) {
                #pragma unroll
                for (int dx2 = -1; dx2 <= 1; dx2++) {
                    if ((unsigned)(gy+dy) < 256u && (unsigned)(gx+dx2) < 256u)
                        pre = fmaxf(pre, xs[((py+3+dy)*14 + (px+3+dx2))*20 + 3]);
                }
            }
            prelife_out[(b << 16) + (gy << 8) + gx] = (pre > 0.1f) ? 1.f : 0.f;
        }
    }

    // ---- phase 2: MLP ----
    const int kq   = t & 3;         // k-quarter + output channel-quad
    const int jg   = (t >> 2) & 3;  // j-octet within 32-j chunk
    const int quad = t >> 4;        // owns 4 CONSECUTIVE px {4quad..4quad+3}
    const int jg8  = jg << 3;
    const int p0px = quad << 2;

    // bank starts: (4quad*140 + kq*36) mod 32 = 16(quad&1) + 4kq -> uniform
    const float* pp0 = &perc[(p0px    ) * PST + kq*GST];
    const float* pp1 = &perc[(p0px + 1) * PST + kq*GST];
    const float* pp2 = &perc[(p0px + 2) * PST + kq*GST];
    const float* pp3 = &perc[(p0px + 3) * PST + kq*GST];

    // staging addresses: thread handles float4 idx r*256+t of each chunk
    const float* pW   = W0 + ((t >> 3) << 8) + ((t & 7) << 2);
    const int   wbase = (t >> 3) * 144 + ((t & 7) << 2);

    float dx[4][4];
    #pragma unroll
    for (int i = 0; i < 4; i++)
        #pragma unroll
        for (int c = 0; c < 4; c++) dx[i][c] = 0.f;

    // prologue: stage chunk 0
    float4 st0 = *(const float4*)(pW);
    float4 st1 = *(const float4*)(pW +  8192);
    float4 st2 = *(const float4*)(pW + 16384);
    float4 st3 = *(const float4*)(pW + 24576);
    __syncthreads();   // phase-1 xs reads + perc writes complete
    *(float4*)&w0s[wbase      ] = st0;
    *(float4*)&w0s[wbase +  36] = st1;
    *(float4*)&w0s[wbase +  72] = st2;
    *(float4*)&w0s[wbase + 108] = st3;
    __syncthreads();

    #pragma unroll 1
    for (int jc = 0; jc < 8; jc++) {
        // T14: issue next chunk's loads now; latency hides under the FMAs
        if (jc < 7) {
            const float* pN = pW + ((jc + 1) << 5);
            st0 = *(const float4*)(pN);
            st1 = *(const float4*)(pN +  8192);
            st2 = *(const float4*)(pN + 16384);
            st3 = *(const float4*)(pN + 24576);
        }

        float h[4][8];
        #pragma unroll
        for (int i = 0; i < 4; i++)
            #pragma unroll
            for (int jj = 0; jj < 8; jj++) h[i][jj] = 0.f;

        #pragma unroll
        for (int k4 = 0; k4 < 32; k4 += 4) {
            float4 pA0 = *(const float4*)&pp0[k4];
            float4 pA1 = *(const float4*)&pp1[k4];
            float4 pA2 = *(const float4*)&pp2[k4];
            float4 pA3 = *(const float4*)&pp3[k4];
            #pragma unroll
            for (int kk = 0; kk < 4; kk++) {
                float a0 = kk==0?pA0.x : kk==1?pA0.y : kk==2?pA0.z : pA0.w;
                float a1 = kk==0?pA1.x : kk==1?pA1.y : kk==2?pA1.z : pA1.w;
                float a2 = kk==0?pA2.x : kk==1?pA2.y : kk==2?pA2.z : pA2.w;
                float a3 = kk==0?pA3.x : kk==1?pA3.y : kk==2?pA3.z : pA3.w;
                const float* wr = &w0s[((k4 + kk)*4 + kq)*36 + jg8];
                float4 wA = *(const float4*)wr;
                float4 wB = *(const float4*)(wr + 4);
                #pragma unroll
                for (int i = 0; i < 4; i++) {
                    float ai = i==0?a0 : i==1?a1 : i==2?a2 : a3;
                    h[i][0] = fmaf(ai, wA.x, h[i][0]);
                    h[i][1] = fmaf(ai, wA.y, h[i][1]);
                    h[i][2] = fmaf(ai, wA.z, h[i][2]);
                    h[i][3] = fmaf(ai, wA.w, h[i][3]);
                    h[i][4] = fmaf(ai, wB.x, h[i][4]);
                    h[i][5] = fmaf(ai, wB.y, h[i][5]);
                    h[i][6] = fmaf(ai, wB.z, h[i][6]);
                    h[i][7] = fmaf(ai, wB.w, h[i][7]);
                }
            }
        }
        // reduce h over the 4 kq lanes (bits 0-1)
        #pragma unroll
        for (int i = 0; i < 4; i++)
            #pragma unroll
            for (int jj = 0; jj < 8; jj++) {
                h[i][jj] += __shfl_xor(h[i][jj], 1);
                h[i][jj] += __shfl_xor(h[i][jj], 2);
            }
        // bias + relu
        const int jbase = (jc << 5) + jg8;
        float4 bA = *(const float4*)&b0[jbase];
        float4 bB = *(const float4*)&b0[jbase + 4];
        #pragma unroll
        for (int i = 0; i < 4; i++) {
            h[i][0] = fmaxf(h[i][0] + bA.x, 0.f);
            h[i][1] = fmaxf(h[i][1] + bA.y, 0.f);
            h[i][2] = fmaxf(h[i][2] + bA.z, 0.f);
            h[i][3] = fmaxf(h[i][3] + bA.w, 0.f);
            h[i][4] = fmaxf(h[i][4] + bB.x, 0.f);
            h[i][5] = fmaxf(h[i][5] + bB.y, 0.f);
            h[i][6] = fmaxf(h[i][6] + bB.z, 0.f);
            h[i][7] = fmaxf(h[i][7] + bB.w, 0.f);
        }
        // GEMM2: this lane's channel-quad kq*4..+4
        #pragma unroll
        for (int jj = 0; jj < 8; jj++) {
            float4 wv = *(const float4*)&W1[((jbase + jj) << 4) + (kq << 2)];
            #pragma unroll
            for (int i = 0; i < 4; i++) {
                dx[i][0] = fmaf(h[i][jj], wv.x, dx[i][0]);
                dx[i][1] = fmaf(h[i][jj], wv.y, dx[i][1]);
                dx[i][2] = fmaf(h[i][jj], wv.z, dx[i][2]);
                dx[i][3] = fmaf(h[i][jj], wv.w, dx[i][3]);
            }
        }

        __syncthreads();   // all reads of w0s done before overwrite
        if (jc < 7) {
            *(float4*)&w0s[wbase      ] = st0;
            *(float4*)&w0s[wbase +  36] = st1;
            *(float4*)&w0s[wbase +  72] = st2;
            *(float4*)&w0s[wbase + 108] = st3;
            __syncthreads();
        }
    }

    // reduce dx over the 4 jg lanes (bits 2-3)
    #pragma unroll
    for (int i = 0; i < 4; i++)
        #pragma unroll
        for (int c = 0; c < 4; c++) {
            dx[i][c] += __shfl_xor(dx[i][c], 4);
            dx[i][c] += __shfl_xor(dx[i][c], 8);
        }

    // writer: pixel 4quad+jg, channels kq*4..+4
    float o0 = jg==0?dx[0][0] : jg==1?dx[1][0] : jg==2?dx[2][0] : dx[3][0];
    float o1 = jg==0?dx[0][1] : jg==1?dx[1][1] : jg==2?dx[2][1] : dx[3][1];
    float o2 = jg==0?dx[0][2] : jg==1?dx[1][2] : jg==2?dx[2][2] : dx[3][2];
    float o3 = jg==0?dx[0][3] : jg==1?dx[1][3] : jg==2?dx[2][3] : dx[3][3];

    const int pw  = p0px + jg;
    const int ppy = pw >> 3, ppx = pw & 7;
    const int pix2 = (b << 16) + ((ty0 + ppy) << 8) + (tx0 + ppx);
    float fire = (stoch_s[pix2] > 0.5f) ? 1.f : 0.f;
    float4 xc2 = *(const float4*)&perc[pw*PST + (kq << 2)];
    float4 xn;
    xn.x = fmaf(fire, o0, xc2.x);
    xn.y = fmaf(fire, o1, xc2.y);
    xn.z = fmaf(fire, o2, xc2.z);
    xn.w = fmaf(fire, o3, xc2.w);
    *(float4*)&xmid[((size_t)pix2 << 4) + (kq << 2)] = xn;
    if (kq == 0) alpha_out[pix2] = xn.w;   // channel 3
}

// In-place life masking: reads alpha_new from the separate plane (race-free).
__global__ void step_mask(float* __restrict__ xbuf,
                          const float* __restrict__ alpha,
                          const float* __restrict__ prelife,
                          const float* __restrict__ valid) {
    int pix = blockIdx.x * 256 + threadIdx.x;
    int b = pix >> 16;
    int y = (pix >> 8) & 255;
    int x = pix & 255;
    float m = -INFINITY;
    #pragma unroll
    for (int dy = -1; dy <= 1; dy++) {
        #pragma unroll
        for (int dxo = -1; dxo <= 1; dxo++) {
            int yy = y + dy, xx = x + dxo;
            if ((unsigned)yy < 256u && (unsigned)xx < 256u)
                m = fmaxf(m, alpha[(b << 16) + (yy << 8) + xx]);
        }
    }
    float life = (prelife[pix] != 0.f && m > 0.1f) ? 1.f : 0.f;
    float s = life * valid[pix];
    float4* xp = (float4*)&xbuf[(size_t)pix << 4];
    #pragma unroll
    for (int i = 0; i < 4; i++) {
        float4 v = xp[i];
        v.x *= s; v.y *= s; v.z *= s; v.w *= s;
        xp[i] = v;
    }
}

extern "C" void kernel_launch(void* const* d_in, const int* in_sizes, int n_in,
                              void* d_out, int out_size, void* d_ws, size_t ws_size,
                              hipStream_t stream) {
    const float* x0    = (const float*)d_in[0];
    const float* valid = (const float*)d_in[1];
    const float* stoch = (const float*)d_in[2];
    const float* W0    = (const float*)d_in[3];
    const float* b0    = (const float*)d_in[4];
    const float* W1    = (const float*)d_in[5];

    float* ws      = (float*)d_ws;
    float* xA      = ws;                 // 8388608 floats
    float* alpha   = ws + 8388608;       // 524288
    float* prelife = ws + 8912896;       // 524288
    float* filt    = ws + 9437184;       // 294 (+pad)
    float* out     = (float*)d_out;

    init_kernel<<<1, 64, 0, stream>>>(W0, filt);

    const float* src = x0;
    for (int k = 1; k <= 16; k++) {
        float* dst = (k & 1) ? xA : out;   // step 16 (even) lands in d_out
        step_main<<<dim3(32,32,8), 256, 0, stream>>>(
            src, dst, alpha, prelife, filt, W0, b0, W1,
            stoch + (size_t)(k-1)*NPIX);
        step_mask<<<NPIX/256, 256, 0, stream>>>(dst, alpha, prelife, valid);
        src = dst;
    }
}